// Round 3
// baseline (603.768 us; speedup 1.0000x reference)
//
#include <hip/hip_runtime.h>
#include <hip/hip_bf16.h>
#include <stdint.h>

typedef __hip_bfloat16 bf16;
using f32x4 = __attribute__((ext_vector_type(4))) float;
using s16x8 = __attribute__((ext_vector_type(8))) short;
using s16x4 = __attribute__((ext_vector_type(4))) short;

#define MFMA16(A_, B_, C_) __builtin_amdgcn_mfma_f32_16x16x32_bf16((A_), (B_), (C_), 0, 0, 0)

__device__ __forceinline__ void gload16(const void* g, void* l) {
  __builtin_amdgcn_global_load_lds((const __attribute__((address_space(1))) void*)g,
                                   (__attribute__((address_space(3))) void*)l, 16, 0, 0);
}

// ---------------- dtype detector ----------------
// flag=1 -> inputs/outputs fp32; flag=0 -> bf16.
__global__ __launch_bounds__(256) void detect_kernel(const void* __restrict__ x,
                                                     int* __restrict__ flag) {
  __shared__ int cnt;
  if (threadIdx.x == 0) cnt = 0;
  __syncthreads();
  const uint32_t* w = (const uint32_t*)x;
  int local = 0;
#pragma unroll
  for (int i = 0; i < 8; ++i) {
    uint32_t v = w[threadIdx.x * 8 + i];
    uint32_t e = (v >> 7) & 0xFF;
    if (e >= 110 && e <= 135) local++;
  }
  atomicAdd(&cnt, local);
  __syncthreads();
  if (threadIdx.x == 0) *flag = (cnt < 1024) ? 1 : 0;
}

// ---------------- x chunk -> bf16 (vectorized) ----------------
__global__ __launch_bounds__(256) void convert_kernel(const void* __restrict__ x,
                                                      bf16* __restrict__ xb,
                                                      size_t elem_off,
                                                      const int* __restrict__ flag) {
  size_t i = ((size_t)blockIdx.x * 256 + threadIdx.x) * 8;
  if (*flag) {
    const float* xf = (const float*)x + elem_off + i;
    float4 a = ((const float4*)xf)[0];
    float4 b = ((const float4*)xf)[1];
    union { bf16 h[8]; uint4 u; } o;
    o.h[0] = __float2bfloat16(a.x); o.h[1] = __float2bfloat16(a.y);
    o.h[2] = __float2bfloat16(a.z); o.h[3] = __float2bfloat16(a.w);
    o.h[4] = __float2bfloat16(b.x); o.h[5] = __float2bfloat16(b.y);
    o.h[6] = __float2bfloat16(b.z); o.h[7] = __float2bfloat16(b.w);
    *(uint4*)(&xb[i]) = o.u;
  } else {
    *(uint4*)(&xb[i]) = *(const uint4*)((const bf16*)x + elem_off + i);
  }
}

// ---------------- transpose: Wt[n][k] = W[k][n], W is [K][N] ----------------
__global__ __launch_bounds__(256) void transpose_kernel(const void* __restrict__ W,
                                                        bf16* __restrict__ Wt,
                                                        int K, int N,
                                                        const int* __restrict__ flag) {
  int idx = blockIdx.x * 256 + threadIdx.x;
  if (idx >= K * N) return;
  int n = idx / K;
  int k = idx - n * K;
  if (*flag)
    Wt[idx] = __float2bfloat16(((const float*)W)[k * N + n]);
  else
    Wt[idx] = ((const bf16*)W)[k * N + n];
}

// ---------------- GEMM: C[M][N] = A[M][384] * Bt[N][384]^T ----------------
template <int MODE>
__global__ __launch_bounds__(256) void gemm_kernel(
    const bf16* __restrict__ A, const bf16* __restrict__ Bt,
    bf16* __restrict__ qb, bf16* __restrict__ kb, bf16* __restrict__ vb,
    void* __restrict__ outp, const void* __restrict__ bias,
    int r_off, const int* __restrict__ flag) {
  constexpr int K = 384;
  __shared__ bf16 Ash[128 * 32];
  __shared__ bf16 Bsh[128 * 32];
  const int tid = threadIdx.x;
  const int lane = tid & 63;
  const int wave = tid >> 6;
  const int wm = wave & 1, wn = wave >> 1;
  const int l15 = lane & 15, quad = lane >> 4;
  const int n0 = blockIdx.x * 128, m0 = blockIdx.y * 128;

  const int rl = lane >> 2;
  const int slot = lane & 3;
  const int sc = (slot - (lane >> 3)) & 3;
  const size_t lane_goff = (size_t)rl * K + sc * 8;

  const int arow0 = wave * 32;
  const bf16* Ag0 = A + (size_t)(m0 + arow0) * K + lane_goff;
  const bf16* Ag1 = Ag0 + (size_t)16 * K;
  const bf16* Bg0 = Bt + (size_t)(n0 + arow0) * K + lane_goff;
  const bf16* Bg1 = Bg0 + (size_t)16 * K;
  bf16* Al0 = &Ash[arow0 * 32];
  bf16* Al1 = &Ash[(arow0 + 16) * 32];
  bf16* Bl0 = &Bsh[arow0 * 32];
  bf16* Bl1 = &Bsh[(arow0 + 16) * 32];

  const int fc = ((quad + (l15 >> 1)) & 3) * 8;

  const f32x4 z4 = {0.f, 0.f, 0.f, 0.f};
  f32x4 acc[4][4];
#pragma unroll
  for (int i = 0; i < 4; ++i)
#pragma unroll
    for (int j = 0; j < 4; ++j) acc[i][j] = z4;

  for (int kt = 0; kt < 12; ++kt) {
    const int k0 = kt * 32;
    gload16(Ag0 + k0, Al0);
    gload16(Ag1 + k0, Al1);
    gload16(Bg0 + k0, Bl0);
    gload16(Bg1 + k0, Bl1);
    __syncthreads();
    s16x8 af[4], bfr[4];
#pragma unroll
    for (int i = 0; i < 4; ++i) {
      af[i] = *(const s16x8*)(&Ash[(wm * 64 + i * 16 + l15) * 32 + fc]);
      bfr[i] = *(const s16x8*)(&Bsh[(wn * 64 + i * 16 + l15) * 32 + fc]);
    }
#pragma unroll
    for (int i = 0; i < 4; ++i)
#pragma unroll
      for (int j = 0; j < 4; ++j) acc[i][j] = MFMA16(af[i], bfr[j], acc[i][j]);
    __syncthreads();
  }

  const int mbase = m0 + wm * 64;
  const int nbase = n0 + wn * 64;
  if (MODE == 0) {
    const int sel = blockIdx.x / 3;  // 0->Q, 1->K, 2->V
    bf16* dst = (sel == 0) ? qb : ((sel == 1) ? kb : vb);
#pragma unroll
    for (int i = 0; i < 4; ++i) {
#pragma unroll
      for (int j = 0; j < 4; ++j) {
        int n_g = nbase + j * 16 + l15;
        int c = n_g - sel * 384;
        int h = c >> 6, d = c & 63;
#pragma unroll
        for (int r = 0; r < 4; ++r) {
          int m_loc = mbase + i * 16 + quad * 4 + r;
          int b = m_loc >> 8, t = m_loc & 255;
          bf16 bv = __float2bfloat16(acc[i][j][r]);
          int bh = b * 6 + h;
          if (sel < 2)
            dst[(size_t)bh * 16384 + t * 64 + d] = bv;   // [b,h,t,d]
          else
            dst[(size_t)bh * 16384 + d * 256 + t] = bv;  // [b,h,d,t] (V^T)
        }
      }
    }
  } else {
    const int f32io = *flag;
#pragma unroll
    for (int i = 0; i < 4; ++i) {
#pragma unroll
      for (int j = 0; j < 4; ++j) {
        int n_g = nbase + j * 16 + l15;
        float bsv = f32io ? ((const float*)bias)[n_g]
                          : __bfloat162float(((const bf16*)bias)[n_g]);
#pragma unroll
        for (int r = 0; r < 4; ++r) {
          int m_loc = mbase + i * 16 + quad * 4 + r;
          size_t o = (size_t)(r_off + m_loc) * 384 + n_g;
          float val = acc[i][j][r] + bsv;
          if (f32io)
            ((float*)outp)[o] = val;
          else
            ((bf16*)outp)[o] = __float2bfloat16(val);
        }
      }
    }
  }
}

// ---------------- causal attention, fully fused, zero LDS ----------------
// grid: nb*24 blocks (XCD-swizzled); 4 independent waves; wave w owns 16 q-rows.
// Per 32-key chunk t: two S^T tiles via MFMA(A=K,B=Q) (lane: q=l15, keys
// quad*4+r), exp+pack in-register, then PV via MFMA(A=Vt,B=P) using a
// PERMUTED key order pi(quad*8+j) = {quad*4+j | 16+quad*4+(j-4)} so the
// packed S output IS the PV B-fragment (no LDS / no cross-lane P movement).
// Vt A-frag uses the same permutation: two b64 loads at 32t+quad*4 and
// 32t+16+quad*4. K ring-prefetched 1 chunk ahead; V issued at iter top.
__global__ __launch_bounds__(256) void attn_kernel(const bf16* __restrict__ Q,
                                                   const bf16* __restrict__ Kb,
                                                   const bf16* __restrict__ Vt,
                                                   bf16* __restrict__ attn_out) {
  const int tid = threadIdx.x;
  const int lane = tid & 63;
  const int wave = tid >> 6;
  const int l15 = lane & 15, quad = lane >> 4;
  // bijective XCD swizzle: gridDim.x = nb*24 (divisible by 8); the 4 causal
  // blocks sharing one head's K/V become consecutive on one XCD's L2.
  const int nblk = gridDim.x;
  const int blk = (blockIdx.x & 7) * (nblk >> 3) + (blockIdx.x >> 3);
  const int qt = blk & 3;
  const int bh = blk >> 2;
  const int q0 = qt * 64 + wave * 16;
  const size_t base = (size_t)bh * 16384;

  // Q fragments (B-operand: n = l15 = q-row, k = quad*8+j = d)
  s16x8 qf0 = *(const s16x8*)(&Q[base + (q0 + l15) * 64 + quad * 8]);
  s16x8 qf1 = *(const s16x8*)(&Q[base + (q0 + l15) * 64 + 32 + quad * 8]);

  const int ntmax = q0 >> 4;           // wave-uniform last 16-key tile
  const int ktcnt = (ntmax + 2) >> 1;  // number of 32-key chunks (1..8)
  const int tq = q0 + l15;
  const f32x4 z4 = {0.f, 0.f, 0.f, 0.f};
  f32x4 of[4];
#pragma unroll
  for (int dt = 0; dt < 4; ++dt) of[dt] = z4;
  float rsum = 0.f;

  const bf16* Kp = Kb + base + (size_t)l15 * 64 + quad * 8;
  const bf16* Vp = Vt + base + (size_t)l15 * 256 + quad * 4;

  typedef union { s16x8 v; s16x4 q2[2]; } vf_t;
  typedef union { s16x8 v; uint32_t w[4]; } pf_t;

  // K ring, 1 chunk ahead: [buf][tile-half*2 + d-half]
  s16x8 kf[2][4];
#pragma unroll
  for (int hf = 0; hf < 2; ++hf) {
    kf[0][hf * 2 + 0] = *(const s16x8*)(Kp + (size_t)(hf * 16) * 64);
    kf[0][hf * 2 + 1] = *(const s16x8*)(Kp + (size_t)(hf * 16) * 64 + 32);
  }

#pragma unroll
  for (int t = 0; t < 8; ++t) {
    if (t < ktcnt) {  // wave-uniform
      const int cur = t & 1, nxt = cur ^ 1;
      // V fragments for this chunk (issued early; consumed after S+exp)
      vf_t vf[4];
#pragma unroll
      for (int dt = 0; dt < 4; ++dt) {
        vf[dt].q2[0] = *(const s16x4*)(Vp + (size_t)dt * 4096 + t * 32);
        vf[dt].q2[1] = *(const s16x4*)(Vp + (size_t)dt * 4096 + t * 32 + 16);
      }
      // prefetch next chunk's K
      if (t + 1 < ktcnt) {  // wave-uniform
        const bf16* Kn = Kp + (size_t)(t + 1) * 32 * 64;
#pragma unroll
        for (int hf = 0; hf < 2; ++hf) {
          kf[nxt][hf * 2 + 0] = *(const s16x8*)(Kn + (size_t)(hf * 16) * 64);
          kf[nxt][hf * 2 + 1] = *(const s16x8*)(Kn + (size_t)(hf * 16) * 64 + 32);
        }
      }
      // two 16-key S^T tiles -> packed P (this IS the PV B-fragment)
      pf_t pf;
#pragma unroll
      for (int hf = 0; hf < 2; ++hf) {
        const int nt = 2 * t + hf;
        if (nt <= ntmax) {  // wave-uniform
          f32x4 s = MFMA16(kf[cur][hf * 2 + 0], qf0, z4);
          s = MFMA16(kf[cur][hf * 2 + 1], qf1, s);
          const int tk0 = nt * 16 + quad * 4;
          float p0 = (tk0 + 0 <= tq) ? __expf(s[0] * 0.125f) : 0.f;
          float p1 = (tk0 + 1 <= tq) ? __expf(s[1] * 0.125f) : 0.f;
          float p2 = (tk0 + 2 <= tq) ? __expf(s[2] * 0.125f) : 0.f;
          float p3 = (tk0 + 3 <= tq) ? __expf(s[3] * 0.125f) : 0.f;
          rsum += (p0 + p1) + (p2 + p3);
          union { bf16 hh[2]; uint32_t u; } w0, w1;
          w0.hh[0] = __float2bfloat16(p0); w0.hh[1] = __float2bfloat16(p1);
          w1.hh[0] = __float2bfloat16(p2); w1.hh[1] = __float2bfloat16(p3);
          pf.w[hf * 2 + 0] = w0.u;
          pf.w[hf * 2 + 1] = w1.u;
        } else {
          pf.w[hf * 2 + 0] = 0u;
          pf.w[hf * 2 + 1] = 0u;
        }
      }
      // PV: O^T accumulate, permuted key order (matches vf layout)
#pragma unroll
      for (int dt = 0; dt < 4; ++dt) of[dt] = MFMA16(vf[dt].v, pf.v, of[dt]);
    }
  }

  rsum += __shfl_xor(rsum, 16);
  rsum += __shfl_xor(rsum, 32);
  const float inv = 1.0f / rsum;

  const int b = bh / 6;
  const int h = bh - b * 6;
  const size_t orow = (size_t)(b * 256 + q0 + l15) * 384 + h * 64;
#pragma unroll
  for (int dt = 0; dt < 4; ++dt) {
    union { bf16 h4[4]; uint2 u; } o;
#pragma unroll
    for (int r = 0; r < 4; ++r) o.h4[r] = __float2bfloat16(of[dt][r] * inv);
    *(uint2*)(&attn_out[orow + dt * 16 + quad * 4]) = o.u;
  }
}

// ---------------- launcher ----------------
extern "C" void kernel_launch(void* const* d_in, const int* in_sizes, int n_in,
                              void* d_out, int out_size, void* d_ws, size_t ws_size,
                              hipStream_t stream) {
  const void* x = d_in[0];       // [256,256,384]  fp32 or bf16 (detected)
  const void* Wqkv = d_in[1];    // [384,1152]
  const void* Wproj = d_in[2];   // [384,384]
  const void* bproj = d_in[3];   // [384]

  char* ws = (char*)d_ws;
  int* flag = (int*)ws;                ws += 256;
  bf16* Wt_qkv = (bf16*)ws;            ws += (size_t)1152 * 384 * 2;
  bf16* Wt_proj = (bf16*)ws;           ws += (size_t)384 * 384 * 2;

  const size_t per_batch = (size_t)5 * 98304 * 2;  // xb,q,k,vt,attn per batch
  size_t used = (size_t)(ws - (char*)d_ws);
  size_t remain = (ws_size > used) ? (ws_size - used) : 0;
  int NB = (int)(remain / per_batch);
  if (NB > 256) NB = 256;
  if (NB < 1) NB = 1;

  bf16* xb_buf = (bf16*)ws;
  bf16* q_buf = xb_buf + (size_t)NB * 98304;
  bf16* k_buf = q_buf + (size_t)NB * 98304;
  bf16* vt_buf = k_buf + (size_t)NB * 98304;
  bf16* attn_buf = vt_buf + (size_t)NB * 98304;

  detect_kernel<<<1, 256, 0, stream>>>(x, flag);
  transpose_kernel<<<(384 * 1152 + 255) / 256, 256, 0, stream>>>(Wqkv, Wt_qkv, 384, 1152, flag);
  transpose_kernel<<<(384 * 384 + 255) / 256, 256, 0, stream>>>(Wproj, Wt_proj, 384, 384, flag);

  for (int b0 = 0; b0 < 256; b0 += NB) {
    int nb = (256 - b0 < NB) ? (256 - b0) : NB;
    int r_off = b0 * 256;
    convert_kernel<<<nb * 48, 256, 0, stream>>>(x, xb_buf, (size_t)r_off * 384, flag);
    gemm_kernel<0><<<dim3(9, 2 * nb), 256, 0, stream>>>(
        xb_buf, Wt_qkv, q_buf, k_buf, vt_buf, nullptr, nullptr, 0, flag);
    attn_kernel<<<nb * 24, 256, 0, stream>>>(q_buf, k_buf, vt_buf, attn_buf);
    gemm_kernel<1><<<dim3(3, 2 * nb), 256, 0, stream>>>(
        attn_buf, Wt_proj, nullptr, nullptr, nullptr, d_out, bproj, r_off, flag);
  }
}

// Round 5
// 457.170 us; speedup vs baseline: 1.3207x; 1.3207x over previous
//
#include <hip/hip_runtime.h>
#include <hip/hip_bf16.h>
#include <stdint.h>

typedef __hip_bfloat16 bf16;
using f32x4 = __attribute__((ext_vector_type(4))) float;
using s16x8 = __attribute__((ext_vector_type(8))) short;

#define MFMA16(A_, B_, C_) __builtin_amdgcn_mfma_f32_16x16x32_bf16((A_), (B_), (C_), 0, 0, 0)

__device__ __forceinline__ void gload16(const void* g, void* l) {
  __builtin_amdgcn_global_load_lds((const __attribute__((address_space(1))) void*)g,
                                   (__attribute__((address_space(3))) void*)l, 16, 0, 0);
}

// ---------------- dtype detector ----------------
// flag=1 -> inputs/outputs fp32; flag=0 -> bf16.
__global__ __launch_bounds__(256) void detect_kernel(const void* __restrict__ x,
                                                     int* __restrict__ flag) {
  __shared__ int cnt;
  if (threadIdx.x == 0) cnt = 0;
  __syncthreads();
  const uint32_t* w = (const uint32_t*)x;
  int local = 0;
#pragma unroll
  for (int i = 0; i < 8; ++i) {
    uint32_t v = w[threadIdx.x * 8 + i];
    uint32_t e = (v >> 7) & 0xFF;
    if (e >= 110 && e <= 135) local++;
  }
  atomicAdd(&cnt, local);
  __syncthreads();
  if (threadIdx.x == 0) *flag = (cnt < 1024) ? 1 : 0;
}

// ---------------- x chunk -> bf16 (vectorized) ----------------
__global__ __launch_bounds__(256) void convert_kernel(const void* __restrict__ x,
                                                      bf16* __restrict__ xb,
                                                      size_t elem_off,
                                                      const int* __restrict__ flag) {
  size_t i = ((size_t)blockIdx.x * 256 + threadIdx.x) * 8;
  if (*flag) {
    const float* xf = (const float*)x + elem_off + i;
    float4 a = ((const float4*)xf)[0];
    float4 b = ((const float4*)xf)[1];
    union { bf16 h[8]; uint4 u; } o;
    o.h[0] = __float2bfloat16(a.x); o.h[1] = __float2bfloat16(a.y);
    o.h[2] = __float2bfloat16(a.z); o.h[3] = __float2bfloat16(a.w);
    o.h[4] = __float2bfloat16(b.x); o.h[5] = __float2bfloat16(b.y);
    o.h[6] = __float2bfloat16(b.z); o.h[7] = __float2bfloat16(b.w);
    *(uint4*)(&xb[i]) = o.u;
  } else {
    *(uint4*)(&xb[i]) = *(const uint4*)((const bf16*)x + elem_off + i);
  }
}

// ---------------- transpose: Wt[n][k] = W[k][n], W is [K][N] ----------------
__global__ __launch_bounds__(256) void transpose_kernel(const void* __restrict__ W,
                                                        bf16* __restrict__ Wt,
                                                        int K, int N,
                                                        const int* __restrict__ flag) {
  int idx = blockIdx.x * 256 + threadIdx.x;
  if (idx >= K * N) return;
  int n = idx / K;
  int k = idx - n * K;
  if (*flag)
    Wt[idx] = __float2bfloat16(((const float*)W)[k * N + n]);
  else
    Wt[idx] = ((const bf16*)W)[k * N + n];
}

// ---------------- GEMM: C[M][N] = A[M][384] * Bt[N][384]^T ----------------
template <int MODE>
__global__ __launch_bounds__(256) void gemm_kernel(
    const bf16* __restrict__ A, const bf16* __restrict__ Bt,
    bf16* __restrict__ qb, bf16* __restrict__ kb, bf16* __restrict__ vb,
    void* __restrict__ outp, const void* __restrict__ bias,
    int r_off, const int* __restrict__ flag) {
  constexpr int K = 384;
  __shared__ bf16 Ash[128 * 32];
  __shared__ bf16 Bsh[128 * 32];
  const int tid = threadIdx.x;
  const int lane = tid & 63;
  const int wave = tid >> 6;
  const int wm = wave & 1, wn = wave >> 1;
  const int l15 = lane & 15, quad = lane >> 4;
  const int n0 = blockIdx.x * 128, m0 = blockIdx.y * 128;

  const int rl = lane >> 2;
  const int slot = lane & 3;
  const int sc = (slot - (lane >> 3)) & 3;
  const size_t lane_goff = (size_t)rl * K + sc * 8;

  const int arow0 = wave * 32;
  const bf16* Ag0 = A + (size_t)(m0 + arow0) * K + lane_goff;
  const bf16* Ag1 = Ag0 + (size_t)16 * K;
  const bf16* Bg0 = Bt + (size_t)(n0 + arow0) * K + lane_goff;
  const bf16* Bg1 = Bg0 + (size_t)16 * K;
  bf16* Al0 = &Ash[arow0 * 32];
  bf16* Al1 = &Ash[(arow0 + 16) * 32];
  bf16* Bl0 = &Bsh[arow0 * 32];
  bf16* Bl1 = &Bsh[(arow0 + 16) * 32];

  const int fc = ((quad + (l15 >> 1)) & 3) * 8;

  const f32x4 z4 = {0.f, 0.f, 0.f, 0.f};
  f32x4 acc[4][4];
#pragma unroll
  for (int i = 0; i < 4; ++i)
#pragma unroll
    for (int j = 0; j < 4; ++j) acc[i][j] = z4;

  for (int kt = 0; kt < 12; ++kt) {
    const int k0 = kt * 32;
    gload16(Ag0 + k0, Al0);
    gload16(Ag1 + k0, Al1);
    gload16(Bg0 + k0, Bl0);
    gload16(Bg1 + k0, Bl1);
    __syncthreads();
    s16x8 af[4], bfr[4];
#pragma unroll
    for (int i = 0; i < 4; ++i) {
      af[i] = *(const s16x8*)(&Ash[(wm * 64 + i * 16 + l15) * 32 + fc]);
      bfr[i] = *(const s16x8*)(&Bsh[(wn * 64 + i * 16 + l15) * 32 + fc]);
    }
#pragma unroll
    for (int i = 0; i < 4; ++i)
#pragma unroll
      for (int j = 0; j < 4; ++j) acc[i][j] = MFMA16(af[i], bfr[j], acc[i][j]);
    __syncthreads();
  }

  const int mbase = m0 + wm * 64;
  const int nbase = n0 + wn * 64;
  if (MODE == 0) {
    const int sel = blockIdx.x / 3;  // 0->Q, 1->K, 2->V
    bf16* dst = (sel == 0) ? qb : ((sel == 1) ? kb : vb);
#pragma unroll
    for (int i = 0; i < 4; ++i) {
#pragma unroll
      for (int j = 0; j < 4; ++j) {
        int n_g = nbase + j * 16 + l15;
        int c = n_g - sel * 384;
        int h = c >> 6, d = c & 63;
#pragma unroll
        for (int r = 0; r < 4; ++r) {
          int m_loc = mbase + i * 16 + quad * 4 + r;
          int b = m_loc >> 8, t = m_loc & 255;
          bf16 bv = __float2bfloat16(acc[i][j][r]);
          int bh = b * 6 + h;
          if (sel < 2) {
            dst[(size_t)bh * 16384 + t * 64 + d] = bv;   // [b,h,t,d]
          } else {
            // V^T [b,h,d,t'] with per-32-chunk key permutation so the attn
            // PV A-fragment is one contiguous 16B load per lane:
            // pos(r) = q*8+j for key pi(q,j) (pi = quad*4+j | 16+quad*4+(j-4))
            int rr = t & 31;
            int pos = (((rr & 15) >> 2) << 3) | (rr & 3) | ((rr >> 4) << 2);
            int tt = (t & ~31) | pos;
            dst[(size_t)bh * 16384 + d * 256 + tt] = bv;
          }
        }
      }
    }
  } else {
    const int f32io = *flag;
#pragma unroll
    for (int i = 0; i < 4; ++i) {
#pragma unroll
      for (int j = 0; j < 4; ++j) {
        int n_g = nbase + j * 16 + l15;
        float bsv = f32io ? ((const float*)bias)[n_g]
                          : __bfloat162float(((const bf16*)bias)[n_g]);
#pragma unroll
        for (int r = 0; r < 4; ++r) {
          int m_loc = mbase + i * 16 + quad * 4 + r;
          size_t o = (size_t)(r_off + m_loc) * 384 + n_g;
          float val = acc[i][j][r] + bsv;
          if (f32io)
            ((float*)outp)[o] = val;
          else
            ((bf16*)outp)[o] = __float2bfloat16(val);
        }
      }
    }
  }
}

// ---------------- causal attention: zero-LDS, paired chains, deep prefetch --
// grid: nb*12 blocks (bh, pair p); wave w owns TWO 16-row q-tiles of head bh:
//   jA = p*4+w (tiles 0..7) and jB = 15-jA (tiles 8..15).
// Total 32-key chunks per wave = ktA+ktB = 9 for every wave (balanced), and
// the two chains share K/V loads + interleave for ILP. Register-P trick:
// packed S output IS the PV B-fragment under key-permutation pi; V^T is
// stored pre-permuted by the gemm so vf is one s16x8 per dt.
// Pipeline: K ring 3 bufs (2 chunks ahead), V 2 bufs (1 ahead). No LDS.
__global__ __launch_bounds__(256, 3) void attn_kernel(const bf16* __restrict__ Q,
                                                      const bf16* __restrict__ Kb,
                                                      const bf16* __restrict__ Vt,
                                                      bf16* __restrict__ attn_out) {
  const int tid = threadIdx.x;
  const int lane = tid & 63;
  const int wave = tid >> 6;
  const int l15 = lane & 15, quad = lane >> 4;
  const int nblk = gridDim.x;
  int blk = blockIdx.x;
  if ((nblk & 7) == 0)  // bijective XCD swizzle (both blocks of a head -> same XCD L2)
    blk = (blockIdx.x & 7) * (nblk >> 3) + (blockIdx.x >> 3);
  const int p = blk & 1;
  const int bh = blk >> 1;
  const int jA = p * 4 + wave;   // light chain: tiles 0..7
  const int jB = 15 - jA;        // heavy chain: tiles 8..15
  const size_t base = (size_t)bh * 16384;
  const int q0A = jA * 16, q0B = jB * 16;

  // Q fragments (B-operand: n = l15 = q-row, k = quad*8+j = d)
  s16x8 qA0 = *(const s16x8*)(&Q[base + (q0A + l15) * 64 + quad * 8]);
  s16x8 qA1 = *(const s16x8*)(&Q[base + (q0A + l15) * 64 + 32 + quad * 8]);
  s16x8 qB0 = *(const s16x8*)(&Q[base + (q0B + l15) * 64 + quad * 8]);
  s16x8 qB1 = *(const s16x8*)(&Q[base + (q0B + l15) * 64 + 32 + quad * 8]);

  const int ktA = (jA + 2) >> 1;   // 1..4 chunks
  const int ktB = (jB + 2) >> 1;   // 4..8 chunks (>= ktA)
  const int tqA = q0A + l15, tqB = q0B + l15;
  const f32x4 z4 = {0.f, 0.f, 0.f, 0.f};

  const bf16* Kp = Kb + base + (size_t)l15 * 64 + quad * 8;
  const bf16* Vp = Vt + base + (size_t)l15 * 256 + quad * 8;

  typedef union { s16x8 v; uint32_t w[4]; } pf_t;

  // K ring (3 bufs, 2 ahead): [buf][hf*2 + d-half]; V ring (2 bufs, 1 ahead)
  s16x8 kf[3][4];
  s16x8 vf[2][4];
#pragma unroll
  for (int i = 0; i < 4; ++i) {
    kf[0][i] = *(const s16x8*)(Kp + (size_t)((i >> 1) * 16) * 64 + (i & 1) * 32);
    kf[1][i] = *(const s16x8*)(Kp + (size_t)(32 + (i >> 1) * 16) * 64 + (i & 1) * 32);
  }
#pragma unroll
  for (int dt = 0; dt < 4; ++dt) vf[0][dt] = *(const s16x8*)(Vp + (size_t)dt * 4096);

  f32x4 ofA[4], ofB[4];
#pragma unroll
  for (int dt = 0; dt < 4; ++dt) { ofA[dt] = z4; ofB[dt] = z4; }
  float rsA = 0.f, rsB = 0.f;

#pragma unroll
  for (int t = 0; t < 8; ++t) {
    if (t < ktB) {  // wave-uniform
      // prefetch K[t+2], V[t+1]
      if (t + 2 < ktB) {
        const bf16* Kn = Kp + (size_t)(t + 2) * 32 * 64;
#pragma unroll
        for (int i = 0; i < 4; ++i)
          kf[(t + 2) % 3][i] = *(const s16x8*)(Kn + (size_t)((i >> 1) * 16) * 64 + (i & 1) * 32);
      }
      if (t + 1 < ktB) {
#pragma unroll
        for (int dt = 0; dt < 4; ++dt)
          vf[(t + 1) & 1][dt] = *(const s16x8*)(Vp + (size_t)dt * 4096 + (t + 1) * 32);
      }
      // ---- chain B (always active while t < ktB) ----
      pf_t pfB;
#pragma unroll
      for (int hf = 0; hf < 2; ++hf) {
        const int nt = 2 * t + hf;
        if (nt <= jB) {  // wave-uniform
          f32x4 s = MFMA16(kf[t % 3][hf * 2 + 0], qB0, z4);
          s = MFMA16(kf[t % 3][hf * 2 + 1], qB1, s);
          const int tk0 = nt * 16 + quad * 4;
          float p0 = (tk0 + 0 <= tqB) ? __expf(s[0] * 0.125f) : 0.f;
          float p1 = (tk0 + 1 <= tqB) ? __expf(s[1] * 0.125f) : 0.f;
          float p2 = (tk0 + 2 <= tqB) ? __expf(s[2] * 0.125f) : 0.f;
          float p3 = (tk0 + 3 <= tqB) ? __expf(s[3] * 0.125f) : 0.f;
          rsB += (p0 + p1) + (p2 + p3);
          union { bf16 hh[2]; uint32_t u; } w0, w1;
          w0.hh[0] = __float2bfloat16(p0); w0.hh[1] = __float2bfloat16(p1);
          w1.hh[0] = __float2bfloat16(p2); w1.hh[1] = __float2bfloat16(p3);
          pfB.w[hf * 2 + 0] = w0.u;
          pfB.w[hf * 2 + 1] = w1.u;
        } else {
          pfB.w[hf * 2 + 0] = 0u;
          pfB.w[hf * 2 + 1] = 0u;
        }
      }
      // ---- chain A (first ktA chunks) ----
      if (t < ktA) {  // wave-uniform
        pf_t pfA;
#pragma unroll
        for (int hf = 0; hf < 2; ++hf) {
          const int nt = 2 * t + hf;
          if (nt <= jA) {  // wave-uniform
            f32x4 s = MFMA16(kf[t % 3][hf * 2 + 0], qA0, z4);
            s = MFMA16(kf[t % 3][hf * 2 + 1], qA1, s);
            const int tk0 = nt * 16 + quad * 4;
            float p0 = (tk0 + 0 <= tqA) ? __expf(s[0] * 0.125f) : 0.f;
            float p1 = (tk0 + 1 <= tqA) ? __expf(s[1] * 0.125f) : 0.f;
            float p2 = (tk0 + 2 <= tqA) ? __expf(s[2] * 0.125f) : 0.f;
            float p3 = (tk0 + 3 <= tqA) ? __expf(s[3] * 0.125f) : 0.f;
            rsA += (p0 + p1) + (p2 + p3);
            union { bf16 hh[2]; uint32_t u; } w0, w1;
            w0.hh[0] = __float2bfloat16(p0); w0.hh[1] = __float2bfloat16(p1);
            w1.hh[0] = __float2bfloat16(p2); w1.hh[1] = __float2bfloat16(p3);
            pfA.w[hf * 2 + 0] = w0.u;
            pfA.w[hf * 2 + 1] = w1.u;
          } else {
            pfA.w[hf * 2 + 0] = 0u;
            pfA.w[hf * 2 + 1] = 0u;
          }
        }
#pragma unroll
        for (int dt = 0; dt < 4; ++dt) ofA[dt] = MFMA16(vf[t & 1][dt], pfA.v, ofA[dt]);
      }
#pragma unroll
      for (int dt = 0; dt < 4; ++dt) ofB[dt] = MFMA16(vf[t & 1][dt], pfB.v, ofB[dt]);
    }
  }

  rsA += __shfl_xor(rsA, 16);
  rsA += __shfl_xor(rsA, 32);
  rsB += __shfl_xor(rsB, 16);
  rsB += __shfl_xor(rsB, 32);
  const float invA = 1.0f / rsA;
  const float invB = 1.0f / rsB;

  const int b = bh / 6;
  const int h = bh - b * 6;
  const size_t orowA = (size_t)(b * 256 + q0A + l15) * 384 + h * 64;
  const size_t orowB = (size_t)(b * 256 + q0B + l15) * 384 + h * 64;
#pragma unroll
  for (int dt = 0; dt < 4; ++dt) {
    union { bf16 h4[4]; uint2 u; } oa, ob;
#pragma unroll
    for (int r = 0; r < 4; ++r) {
      oa.h4[r] = __float2bfloat16(ofA[dt][r] * invA);
      ob.h4[r] = __float2bfloat16(ofB[dt][r] * invB);
    }
    *(uint2*)(&attn_out[orowA + dt * 16 + quad * 4]) = oa.u;
    *(uint2*)(&attn_out[orowB + dt * 16 + quad * 4]) = ob.u;
  }
}

// ---------------- launcher ----------------
extern "C" void kernel_launch(void* const* d_in, const int* in_sizes, int n_in,
                              void* d_out, int out_size, void* d_ws, size_t ws_size,
                              hipStream_t stream) {
  const void* x = d_in[0];       // [256,256,384]  fp32 or bf16 (detected)
  const void* Wqkv = d_in[1];    // [384,1152]
  const void* Wproj = d_in[2];   // [384,384]
  const void* bproj = d_in[3];   // [384]

  char* ws = (char*)d_ws;
  int* flag = (int*)ws;                ws += 256;
  bf16* Wt_qkv = (bf16*)ws;            ws += (size_t)1152 * 384 * 2;
  bf16* Wt_proj = (bf16*)ws;           ws += (size_t)384 * 384 * 2;

  const size_t per_batch = (size_t)5 * 98304 * 2;  // xb,q,k,vt,attn per batch
  size_t used = (size_t)(ws - (char*)d_ws);
  size_t remain = (ws_size > used) ? (ws_size - used) : 0;
  int NB = (int)(remain / per_batch);
  if (NB > 256) NB = 256;
  if (NB < 1) NB = 1;

  bf16* xb_buf = (bf16*)ws;
  bf16* q_buf = xb_buf + (size_t)NB * 98304;
  bf16* k_buf = q_buf + (size_t)NB * 98304;
  bf16* vt_buf = k_buf + (size_t)NB * 98304;
  bf16* attn_buf = vt_buf + (size_t)NB * 98304;

  detect_kernel<<<1, 256, 0, stream>>>(x, flag);
  transpose_kernel<<<(384 * 1152 + 255) / 256, 256, 0, stream>>>(Wqkv, Wt_qkv, 384, 1152, flag);
  transpose_kernel<<<(384 * 384 + 255) / 256, 256, 0, stream>>>(Wproj, Wt_proj, 384, 384, flag);

  for (int b0 = 0; b0 < 256; b0 += NB) {
    int nb = (256 - b0 < NB) ? (256 - b0) : NB;
    int r_off = b0 * 256;
    convert_kernel<<<nb * 48, 256, 0, stream>>>(x, xb_buf, (size_t)r_off * 384, flag);
    gemm_kernel<0><<<dim3(9, 2 * nb), 256, 0, stream>>>(
        xb_buf, Wt_qkv, q_buf, k_buf, vt_buf, nullptr, nullptr, 0, flag);
    attn_kernel<<<nb * 12, 256, 0, stream>>>(q_buf, k_buf, vt_buf, attn_buf);
    gemm_kernel<1><<<dim3(3, 2 * nb), 256, 0, stream>>>(
        attn_buf, Wt_proj, nullptr, nullptr, nullptr, d_out, bproj, r_off, flag);
  }
}

// Round 6
// 435.404 us; speedup vs baseline: 1.3867x; 1.0500x over previous
//
#include <hip/hip_runtime.h>
#include <hip/hip_bf16.h>
#include <stdint.h>

typedef __hip_bfloat16 bf16;
using f32x4 = __attribute__((ext_vector_type(4))) float;
using s16x8 = __attribute__((ext_vector_type(8))) short;

#define MFMA16(A_, B_, C_) __builtin_amdgcn_mfma_f32_16x16x32_bf16((A_), (B_), (C_), 0, 0, 0)

__device__ __forceinline__ void gload16(const void* g, void* l) {
  __builtin_amdgcn_global_load_lds((const __attribute__((address_space(1))) void*)g,
                                   (__attribute__((address_space(3))) void*)l, 16, 0, 0);
}

// ---------------- dtype detector ----------------
// flag=1 -> inputs/outputs fp32; flag=0 -> bf16.
__global__ __launch_bounds__(256) void detect_kernel(const void* __restrict__ x,
                                                     int* __restrict__ flag) {
  __shared__ int cnt;
  if (threadIdx.x == 0) cnt = 0;
  __syncthreads();
  const uint32_t* w = (const uint32_t*)x;
  int local = 0;
#pragma unroll
  for (int i = 0; i < 8; ++i) {
    uint32_t v = w[threadIdx.x * 8 + i];
    uint32_t e = (v >> 7) & 0xFF;
    if (e >= 110 && e <= 135) local++;
  }
  atomicAdd(&cnt, local);
  __syncthreads();
  if (threadIdx.x == 0) *flag = (cnt < 1024) ? 1 : 0;
}

// ---------------- x chunk -> bf16 (vectorized) ----------------
__global__ __launch_bounds__(256) void convert_kernel(const void* __restrict__ x,
                                                      bf16* __restrict__ xb,
                                                      size_t elem_off,
                                                      const int* __restrict__ flag) {
  size_t i = ((size_t)blockIdx.x * 256 + threadIdx.x) * 8;
  if (*flag) {
    const float* xf = (const float*)x + elem_off + i;
    float4 a = ((const float4*)xf)[0];
    float4 b = ((const float4*)xf)[1];
    union { bf16 h[8]; uint4 u; } o;
    o.h[0] = __float2bfloat16(a.x); o.h[1] = __float2bfloat16(a.y);
    o.h[2] = __float2bfloat16(a.z); o.h[3] = __float2bfloat16(a.w);
    o.h[4] = __float2bfloat16(b.x); o.h[5] = __float2bfloat16(b.y);
    o.h[6] = __float2bfloat16(b.z); o.h[7] = __float2bfloat16(b.w);
    *(uint4*)(&xb[i]) = o.u;
  } else {
    *(uint4*)(&xb[i]) = *(const uint4*)((const bf16*)x + elem_off + i);
  }
}

// ---------------- transpose: Wt[n][k] = W[k][n], W is [K][N] ----------------
__global__ __launch_bounds__(256) void transpose_kernel(const void* __restrict__ W,
                                                        bf16* __restrict__ Wt,
                                                        int K, int N,
                                                        const int* __restrict__ flag) {
  int idx = blockIdx.x * 256 + threadIdx.x;
  if (idx >= K * N) return;
  int n = idx / K;
  int k = idx - n * K;
  if (*flag)
    Wt[idx] = __float2bfloat16(((const float*)W)[k * N + n]);
  else
    Wt[idx] = ((const bf16*)W)[k * N + n];
}

// ---------------- GEMM: C[M][N] = A[M][384] * Bt[N][384]^T ----------------
// Grid is (X, Y) with X in {9,3}; consecutive x-fastest linear indices share
// one 128-row A panel. Bijective chunked XCD swizzle (m204 form) gives each
// XCD a contiguous run of panels so panel-sharing blocks hit one L2.
template <int MODE>
__global__ __launch_bounds__(256) void gemm_kernel(
    const bf16* __restrict__ A, const bf16* __restrict__ Bt,
    bf16* __restrict__ qb, bf16* __restrict__ kb, bf16* __restrict__ vb,
    void* __restrict__ outp, const void* __restrict__ bias,
    int r_off, const int* __restrict__ flag) {
  constexpr int K = 384;
  __shared__ bf16 Ash[128 * 32];
  __shared__ bf16 Bsh[128 * 32];
  const int tid = threadIdx.x;
  const int lane = tid & 63;
  const int wave = tid >> 6;
  const int wm = wave & 1, wn = wave >> 1;
  const int l15 = lane & 15, quad = lane >> 4;

  // ---- chunked XCD swizzle on linearized (x-fastest) block index ----
  const int nlin = gridDim.x * gridDim.y;
  const int orig = blockIdx.y * gridDim.x + blockIdx.x;
  const int xcd = orig & 7;
  const int q8 = nlin >> 3, r8 = nlin & 7;
  const int lin = (xcd < r8 ? xcd * (q8 + 1) : r8 * (q8 + 1) + (xcd - r8) * q8) + (orig >> 3);
  const int bx = lin % gridDim.x;
  const int by = lin / gridDim.x;
  const int n0 = bx * 128, m0 = by * 128;

  const int rl = lane >> 2;
  const int slot = lane & 3;
  const int sc = (slot - (lane >> 3)) & 3;
  const size_t lane_goff = (size_t)rl * K + sc * 8;

  const int arow0 = wave * 32;
  const bf16* Ag0 = A + (size_t)(m0 + arow0) * K + lane_goff;
  const bf16* Ag1 = Ag0 + (size_t)16 * K;
  const bf16* Bg0 = Bt + (size_t)(n0 + arow0) * K + lane_goff;
  const bf16* Bg1 = Bg0 + (size_t)16 * K;
  bf16* Al0 = &Ash[arow0 * 32];
  bf16* Al1 = &Ash[(arow0 + 16) * 32];
  bf16* Bl0 = &Bsh[arow0 * 32];
  bf16* Bl1 = &Bsh[(arow0 + 16) * 32];

  const int fc = ((quad + (l15 >> 1)) & 3) * 8;

  const f32x4 z4 = {0.f, 0.f, 0.f, 0.f};
  f32x4 acc[4][4];
#pragma unroll
  for (int i = 0; i < 4; ++i)
#pragma unroll
    for (int j = 0; j < 4; ++j) acc[i][j] = z4;

  for (int kt = 0; kt < 12; ++kt) {
    const int k0 = kt * 32;
    gload16(Ag0 + k0, Al0);
    gload16(Ag1 + k0, Al1);
    gload16(Bg0 + k0, Bl0);
    gload16(Bg1 + k0, Bl1);
    __syncthreads();
    s16x8 af[4], bfr[4];
#pragma unroll
    for (int i = 0; i < 4; ++i) {
      af[i] = *(const s16x8*)(&Ash[(wm * 64 + i * 16 + l15) * 32 + fc]);
      bfr[i] = *(const s16x8*)(&Bsh[(wn * 64 + i * 16 + l15) * 32 + fc]);
    }
#pragma unroll
    for (int i = 0; i < 4; ++i)
#pragma unroll
      for (int j = 0; j < 4; ++j) acc[i][j] = MFMA16(af[i], bfr[j], acc[i][j]);
    __syncthreads();
  }

  const int mbase = m0 + wm * 64;
  const int nbase = n0 + wn * 64;
  if (MODE == 0) {
    const int sel = bx / 3;  // 0->Q, 1->K, 2->V
    bf16* dst = (sel == 0) ? qb : ((sel == 1) ? kb : vb);
#pragma unroll
    for (int i = 0; i < 4; ++i) {
#pragma unroll
      for (int j = 0; j < 4; ++j) {
        int n_g = nbase + j * 16 + l15;
        int c = n_g - sel * 384;
        int h = c >> 6, d = c & 63;
#pragma unroll
        for (int r = 0; r < 4; ++r) {
          int m_loc = mbase + i * 16 + quad * 4 + r;
          int b = m_loc >> 8, t = m_loc & 255;
          bf16 bv = __float2bfloat16(acc[i][j][r]);
          int bh = b * 6 + h;
          if (sel < 2) {
            dst[(size_t)bh * 16384 + t * 64 + d] = bv;   // [b,h,t,d]
          } else {
            // V^T [b,h,d,t'] with per-32-chunk key permutation so the attn
            // PV A-fragment is one contiguous 16B load per lane:
            // pos(r) = q*8+j for key pi(q,j) (pi = quad*4+j | 16+quad*4+(j-4))
            int rr = t & 31;
            int pos = (((rr & 15) >> 2) << 3) | (rr & 3) | ((rr >> 4) << 2);
            int tt = (t & ~31) | pos;
            dst[(size_t)bh * 16384 + d * 256 + tt] = bv;
          }
        }
      }
    }
  } else {
    const int f32io = *flag;
#pragma unroll
    for (int i = 0; i < 4; ++i) {
#pragma unroll
      for (int j = 0; j < 4; ++j) {
        int n_g = nbase + j * 16 + l15;
        float bsv = f32io ? ((const float*)bias)[n_g]
                          : __bfloat162float(((const bf16*)bias)[n_g]);
#pragma unroll
        for (int r = 0; r < 4; ++r) {
          int m_loc = mbase + i * 16 + quad * 4 + r;
          size_t o = (size_t)(r_off + m_loc) * 384 + n_g;
          float val = acc[i][j][r] + bsv;
          if (f32io)
            ((float*)outp)[o] = val;
          else
            ((bf16*)outp)[o] = __float2bfloat16(val);
        }
      }
    }
  }
}

// ---------------- causal attention: zero-LDS, paired chains, deep prefetch --
// grid: nb*12 blocks (bh, pair p); wave w owns TWO 16-row q-tiles of head bh:
//   jA = p*4+w (tiles 0..7) and jB = 15-jA (tiles 8..15).
// Total 32-key chunks per wave = ktA+ktB = 9 for every wave (balanced), and
// the two chains share K/V loads + interleave for ILP. Register-P trick:
// packed S output IS the PV B-fragment under key-permutation pi; V^T is
// stored pre-permuted by the gemm so vf is one s16x8 per dt.
// Pipeline: K ring 3 bufs (2 chunks ahead), V 2 bufs (1 ahead). No LDS.
__global__ __launch_bounds__(256, 3) void attn_kernel(const bf16* __restrict__ Q,
                                                      const bf16* __restrict__ Kb,
                                                      const bf16* __restrict__ Vt,
                                                      bf16* __restrict__ attn_out) {
  const int tid = threadIdx.x;
  const int lane = tid & 63;
  const int wave = tid >> 6;
  const int l15 = lane & 15, quad = lane >> 4;
  const int nblk = gridDim.x;
  int blk = blockIdx.x;
  if ((nblk & 7) == 0)  // bijective XCD swizzle (both blocks of a head -> same XCD L2)
    blk = (blockIdx.x & 7) * (nblk >> 3) + (blockIdx.x >> 3);
  const int p = blk & 1;
  const int bh = blk >> 1;
  const int jA = p * 4 + wave;   // light chain: tiles 0..7
  const int jB = 15 - jA;        // heavy chain: tiles 8..15
  const size_t base = (size_t)bh * 16384;
  const int q0A = jA * 16, q0B = jB * 16;

  // Q fragments (B-operand: n = l15 = q-row, k = quad*8+j = d)
  s16x8 qA0 = *(const s16x8*)(&Q[base + (q0A + l15) * 64 + quad * 8]);
  s16x8 qA1 = *(const s16x8*)(&Q[base + (q0A + l15) * 64 + 32 + quad * 8]);
  s16x8 qB0 = *(const s16x8*)(&Q[base + (q0B + l15) * 64 + quad * 8]);
  s16x8 qB1 = *(const s16x8*)(&Q[base + (q0B + l15) * 64 + 32 + quad * 8]);

  const int ktA = (jA + 2) >> 1;   // 1..4 chunks
  const int ktB = (jB + 2) >> 1;   // 4..8 chunks (>= ktA)
  const int tqA = q0A + l15, tqB = q0B + l15;
  const f32x4 z4 = {0.f, 0.f, 0.f, 0.f};

  const bf16* Kp = Kb + base + (size_t)l15 * 64 + quad * 8;
  const bf16* Vp = Vt + base + (size_t)l15 * 256 + quad * 8;

  typedef union { s16x8 v; uint32_t w[4]; } pf_t;

  // K ring (3 bufs, 2 ahead): [buf][hf*2 + d-half]; V ring (2 bufs, 1 ahead)
  s16x8 kf[3][4];
  s16x8 vf[2][4];
#pragma unroll
  for (int i = 0; i < 4; ++i) {
    kf[0][i] = *(const s16x8*)(Kp + (size_t)((i >> 1) * 16) * 64 + (i & 1) * 32);
    kf[1][i] = *(const s16x8*)(Kp + (size_t)(32 + (i >> 1) * 16) * 64 + (i & 1) * 32);
  }
#pragma unroll
  for (int dt = 0; dt < 4; ++dt) vf[0][dt] = *(const s16x8*)(Vp + (size_t)dt * 4096);

  f32x4 ofA[4], ofB[4];
#pragma unroll
  for (int dt = 0; dt < 4; ++dt) { ofA[dt] = z4; ofB[dt] = z4; }
  float rsA = 0.f, rsB = 0.f;

#pragma unroll
  for (int t = 0; t < 8; ++t) {
    if (t < ktB) {  // wave-uniform
      // prefetch K[t+2], V[t+1]
      if (t + 2 < ktB) {
        const bf16* Kn = Kp + (size_t)(t + 2) * 32 * 64;
#pragma unroll
        for (int i = 0; i < 4; ++i)
          kf[(t + 2) % 3][i] = *(const s16x8*)(Kn + (size_t)((i >> 1) * 16) * 64 + (i & 1) * 32);
      }
      if (t + 1 < ktB) {
#pragma unroll
        for (int dt = 0; dt < 4; ++dt)
          vf[(t + 1) & 1][dt] = *(const s16x8*)(Vp + (size_t)dt * 4096 + (t + 1) * 32);
      }
      // ---- chain B (always active while t < ktB) ----
      pf_t pfB;
#pragma unroll
      for (int hf = 0; hf < 2; ++hf) {
        const int nt = 2 * t + hf;
        if (nt <= jB) {  // wave-uniform
          f32x4 s = MFMA16(kf[t % 3][hf * 2 + 0], qB0, z4);
          s = MFMA16(kf[t % 3][hf * 2 + 1], qB1, s);
          const int tk0 = nt * 16 + quad * 4;
          float p0 = (tk0 + 0 <= tqB) ? __expf(s[0] * 0.125f) : 0.f;
          float p1 = (tk0 + 1 <= tqB) ? __expf(s[1] * 0.125f) : 0.f;
          float p2 = (tk0 + 2 <= tqB) ? __expf(s[2] * 0.125f) : 0.f;
          float p3 = (tk0 + 3 <= tqB) ? __expf(s[3] * 0.125f) : 0.f;
          rsB += (p0 + p1) + (p2 + p3);
          union { bf16 hh[2]; uint32_t u; } w0, w1;
          w0.hh[0] = __float2bfloat16(p0); w0.hh[1] = __float2bfloat16(p1);
          w1.hh[0] = __float2bfloat16(p2); w1.hh[1] = __float2bfloat16(p3);
          pfB.w[hf * 2 + 0] = w0.u;
          pfB.w[hf * 2 + 1] = w1.u;
        } else {
          pfB.w[hf * 2 + 0] = 0u;
          pfB.w[hf * 2 + 1] = 0u;
        }
      }
      // ---- chain A (first ktA chunks) ----
      if (t < ktA) {  // wave-uniform
        pf_t pfA;
#pragma unroll
        for (int hf = 0; hf < 2; ++hf) {
          const int nt = 2 * t + hf;
          if (nt <= jA) {  // wave-uniform
            f32x4 s = MFMA16(kf[t % 3][hf * 2 + 0], qA0, z4);
            s = MFMA16(kf[t % 3][hf * 2 + 1], qA1, s);
            const int tk0 = nt * 16 + quad * 4;
            float p0 = (tk0 + 0 <= tqA) ? __expf(s[0] * 0.125f) : 0.f;
            float p1 = (tk0 + 1 <= tqA) ? __expf(s[1] * 0.125f) : 0.f;
            float p2 = (tk0 + 2 <= tqA) ? __expf(s[2] * 0.125f) : 0.f;
            float p3 = (tk0 + 3 <= tqA) ? __expf(s[3] * 0.125f) : 0.f;
            rsA += (p0 + p1) + (p2 + p3);
            union { bf16 hh[2]; uint32_t u; } w0, w1;
            w0.hh[0] = __float2bfloat16(p0); w0.hh[1] = __float2bfloat16(p1);
            w1.hh[0] = __float2bfloat16(p2); w1.hh[1] = __float2bfloat16(p3);
            pfA.w[hf * 2 + 0] = w0.u;
            pfA.w[hf * 2 + 1] = w1.u;
          } else {
            pfA.w[hf * 2 + 0] = 0u;
            pfA.w[hf * 2 + 1] = 0u;
          }
        }
#pragma unroll
        for (int dt = 0; dt < 4; ++dt) ofA[dt] = MFMA16(vf[t & 1][dt], pfA.v, ofA[dt]);
      }
#pragma unroll
      for (int dt = 0; dt < 4; ++dt) ofB[dt] = MFMA16(vf[t & 1][dt], pfB.v, ofB[dt]);
    }
  }

  rsA += __shfl_xor(rsA, 16);
  rsA += __shfl_xor(rsA, 32);
  rsB += __shfl_xor(rsB, 16);
  rsB += __shfl_xor(rsB, 32);
  const float invA = 1.0f / rsA;
  const float invB = 1.0f / rsB;

  const int b = bh / 6;
  const int h = bh - b * 6;
  const size_t orowA = (size_t)(b * 256 + q0A + l15) * 384 + h * 64;
  const size_t orowB = (size_t)(b * 256 + q0B + l15) * 384 + h * 64;
#pragma unroll
  for (int dt = 0; dt < 4; ++dt) {
    union { bf16 h4[4]; uint2 u; } oa, ob;
#pragma unroll
    for (int r = 0; r < 4; ++r) {
      oa.h4[r] = __float2bfloat16(ofA[dt][r] * invA);
      ob.h4[r] = __float2bfloat16(ofB[dt][r] * invB);
    }
    *(uint2*)(&attn_out[orowA + dt * 16 + quad * 4]) = oa.u;
    *(uint2*)(&attn_out[orowB + dt * 16 + quad * 4]) = ob.u;
  }
}

// ---------------- launcher ----------------
extern "C" void kernel_launch(void* const* d_in, const int* in_sizes, int n_in,
                              void* d_out, int out_size, void* d_ws, size_t ws_size,
                              hipStream_t stream) {
  const void* x = d_in[0];       // [256,256,384]  fp32 or bf16 (detected)
  const void* Wqkv = d_in[1];    // [384,1152]
  const void* Wproj = d_in[2];   // [384,384]
  const void* bproj = d_in[3];   // [384]

  char* ws = (char*)d_ws;
  int* flag = (int*)ws;                ws += 256;
  bf16* Wt_qkv = (bf16*)ws;            ws += (size_t)1152 * 384 * 2;
  bf16* Wt_proj = (bf16*)ws;           ws += (size_t)384 * 384 * 2;

  const size_t per_batch = (size_t)5 * 98304 * 2;  // xb,q,k,vt,attn per batch
  size_t used = (size_t)(ws - (char*)d_ws);
  size_t remain = (ws_size > used) ? (ws_size - used) : 0;
  int NB = (int)(remain / per_batch);
  if (NB > 256) NB = 256;
  if (NB < 1) NB = 1;

  bf16* xb_buf = (bf16*)ws;
  bf16* q_buf = xb_buf + (size_t)NB * 98304;
  bf16* k_buf = q_buf + (size_t)NB * 98304;
  bf16* vt_buf = k_buf + (size_t)NB * 98304;
  bf16* attn_buf = vt_buf + (size_t)NB * 98304;

  detect_kernel<<<1, 256, 0, stream>>>(x, flag);
  transpose_kernel<<<(384 * 1152 + 255) / 256, 256, 0, stream>>>(Wqkv, Wt_qkv, 384, 1152, flag);
  transpose_kernel<<<(384 * 384 + 255) / 256, 256, 0, stream>>>(Wproj, Wt_proj, 384, 384, flag);

  for (int b0 = 0; b0 < 256; b0 += NB) {
    int nb = (256 - b0 < NB) ? (256 - b0) : NB;
    int r_off = b0 * 256;
    convert_kernel<<<nb * 48, 256, 0, stream>>>(x, xb_buf, (size_t)r_off * 384, flag);
    gemm_kernel<0><<<dim3(9, 2 * nb), 256, 0, stream>>>(
        xb_buf, Wt_qkv, q_buf, k_buf, vt_buf, nullptr, nullptr, 0, flag);
    attn_kernel<<<nb * 12, 256, 0, stream>>>(q_buf, k_buf, vt_buf, attn_buf);
    gemm_kernel<1><<<dim3(3, 2 * nb), 256, 0, stream>>>(
        attn_buf, Wt_proj, nullptr, nullptr, nullptr, d_out, bproj, r_off, flag);
  }
}